// Round 1
// baseline (134.113 us; speedup 1.0000x reference)
//
#include <hip/hip_runtime.h>
#include <stdint.h>

// Problem constants
constexpr int ROWS = 64;
constexpr int D = 1 << 19;          // 256*2048 = 524288 per row
constexpr uint32_t KSEL = 52428;    // int(0.1 * D)
constexpr int BPR = 32;             // blocks per row for scan passes
constexpr int CHUNK = D / BPR;      // 16384 elements per block

// Monotonic key: larger float -> larger uint
__device__ __forceinline__ uint32_t mono(uint32_t f) {
    uint32_t m = (uint32_t)((int32_t)f >> 31) | 0x80000000u;
    return f ^ m;
}

// Pass 1: 12-bit histogram of top bits of the key, per row.
__global__ __launch_bounds__(256) void hist_pass1(const uint32_t* __restrict__ x,
                                                  uint32_t* __restrict__ hist) {
    __shared__ uint32_t lh[4096];
    for (int i = threadIdx.x; i < 4096; i += 256) lh[i] = 0;
    __syncthreads();
    int row = blockIdx.x / BPR, chunk = blockIdx.x % BPR;
    const uint4* p = (const uint4*)(x + (size_t)row * D + (size_t)chunk * CHUNK);
    for (int i = threadIdx.x; i < CHUNK / 4; i += 256) {
        uint4 v = p[i];
        atomicAdd(&lh[mono(v.x) >> 20], 1u);
        atomicAdd(&lh[mono(v.y) >> 20], 1u);
        atomicAdd(&lh[mono(v.z) >> 20], 1u);
        atomicAdd(&lh[mono(v.w) >> 20], 1u);
    }
    __syncthreads();
    uint32_t* h = hist + row * 4096;
    for (int i = threadIdx.x; i < 4096; i += 256) {
        uint32_t c = lh[i];
        if (c) atomicAdd(&h[i], c);
    }
}

// Pass 2: among elements matching 12-bit prefix, histogram bits 19..8.
__global__ __launch_bounds__(256) void hist_pass2(const uint32_t* __restrict__ x,
                                                  const uint32_t* __restrict__ sel1,
                                                  uint32_t* __restrict__ hist) {
    __shared__ uint32_t lh[4096];
    for (int i = threadIdx.x; i < 4096; i += 256) lh[i] = 0;
    __syncthreads();
    int row = blockIdx.x / BPR, chunk = blockIdx.x % BPR;
    uint32_t b1 = sel1[row];
    const uint4* p = (const uint4*)(x + (size_t)row * D + (size_t)chunk * CHUNK);
    for (int i = threadIdx.x; i < CHUNK / 4; i += 256) {
        uint4 v = p[i];
        uint32_t u;
        u = mono(v.x); if ((u >> 20) == b1) atomicAdd(&lh[(u >> 8) & 0xFFFu], 1u);
        u = mono(v.y); if ((u >> 20) == b1) atomicAdd(&lh[(u >> 8) & 0xFFFu], 1u);
        u = mono(v.z); if ((u >> 20) == b1) atomicAdd(&lh[(u >> 8) & 0xFFFu], 1u);
        u = mono(v.w); if ((u >> 20) == b1) atomicAdd(&lh[(u >> 8) & 0xFFFu], 1u);
    }
    __syncthreads();
    uint32_t* h = hist + row * 4096;
    for (int i = threadIdx.x; i < 4096; i += 256) {
        uint32_t c = lh[i];
        if (c) atomicAdd(&h[i], c);
    }
}

// Pass 3: among elements matching 24-bit prefix, histogram low byte.
__global__ __launch_bounds__(256) void hist_pass3(const uint32_t* __restrict__ x,
                                                  const uint32_t* __restrict__ sel1,
                                                  const uint32_t* __restrict__ sel2,
                                                  uint32_t* __restrict__ hist) {
    __shared__ uint32_t lh[256];
    lh[threadIdx.x] = 0;
    __syncthreads();
    int row = blockIdx.x / BPR, chunk = blockIdx.x % BPR;
    uint32_t pref = (sel1[row] << 12) | sel2[row];
    const uint4* p = (const uint4*)(x + (size_t)row * D + (size_t)chunk * CHUNK);
    for (int i = threadIdx.x; i < CHUNK / 4; i += 256) {
        uint4 v = p[i];
        uint32_t u;
        u = mono(v.x); if ((u >> 8) == pref) atomicAdd(&lh[u & 0xFFu], 1u);
        u = mono(v.y); if ((u >> 8) == pref) atomicAdd(&lh[u & 0xFFu], 1u);
        u = mono(v.z); if ((u >> 8) == pref) atomicAdd(&lh[u & 0xFFu], 1u);
        u = mono(v.w); if ((u >> 8) == pref) atomicAdd(&lh[u & 0xFFu], 1u);
    }
    __syncthreads();
    uint32_t c = lh[threadIdx.x];
    if (c) atomicAdd(&hist[row * 256 + threadIdx.x], c);
}

// Descending-order rank selection over NB bins: find bin where cumulative
// count (from the top bin down) first reaches k; output bin + residual rank.
template <int NB>
__global__ __launch_bounds__(256) void select_pass(const uint32_t* __restrict__ hist,
                                                   int use_const,
                                                   const uint32_t* __restrict__ rank_in,
                                                   uint32_t* __restrict__ sel_out,
                                                   uint32_t* __restrict__ rank_out) {
    constexpr int PER = NB / 256;
    __shared__ uint32_t sc[256];
    int row = blockIdx.x, t = threadIdx.x;
    const uint32_t* h = hist + row * NB;
    uint32_t k = use_const ? KSEL : rank_in[row];
    int hi = NB - 1 - t * PER;  // thread t owns bins hi .. hi-PER+1 (descending)
    uint32_t s = 0;
    for (int j = 0; j < PER; ++j) s += h[hi - j];
    sc[t] = s;
    __syncthreads();
    for (int off = 1; off < 256; off <<= 1) {
        uint32_t v = (t >= off) ? sc[t - off] : 0u;
        __syncthreads();
        sc[t] += v;
        __syncthreads();
    }
    uint32_t excl = sc[t] - s;  // count in bins above this thread's group
    if (excl < k && excl + s >= k) {
        uint32_t c = excl;
        for (int j = 0; j < PER; ++j) {
            int bin = hi - j;
            uint32_t hb = h[bin];
            c += hb;
            if (c >= k) {
                sel_out[row] = (uint32_t)bin;
                rank_out[row] = k - (c - hb);
                break;
            }
        }
    }
}

// Final 8-bit select: reconstruct exact 32-bit key, decode to float bits.
__global__ __launch_bounds__(256) void select_final(const uint32_t* __restrict__ hist,
                                                    const uint32_t* __restrict__ rank_in,
                                                    const uint32_t* __restrict__ sel1,
                                                    const uint32_t* __restrict__ sel2,
                                                    uint32_t* __restrict__ thr_bits) {
    __shared__ uint32_t sc[256];
    int row = blockIdx.x, t = threadIdx.x;
    const uint32_t* h = hist + row * 256;
    uint32_t k = rank_in[row];
    int bin = 255 - t;
    uint32_t s = h[bin];
    sc[t] = s;
    __syncthreads();
    for (int off = 1; off < 256; off <<= 1) {
        uint32_t v = (t >= off) ? sc[t - off] : 0u;
        __syncthreads();
        sc[t] += v;
        __syncthreads();
    }
    uint32_t excl = sc[t] - s;
    if (excl < k && excl + s >= k) {
        uint32_t u = (sel1[row] << 20) | (sel2[row] << 8) | (uint32_t)bin;
        uint32_t m = (u & 0x80000000u) ? 0x80000000u : 0xFFFFFFFFu;
        thr_bits[row] = u ^ m;  // float bits of exact K-th largest value
    }
}

// Final mask: out = (x < thr) ? x : 0, float4-vectorized.
__global__ __launch_bounds__(256) void mask_pass(const float4* __restrict__ x,
                                                 float4* __restrict__ out,
                                                 const uint32_t* __restrict__ thr_bits) {
    const int64_t total4 = (int64_t)ROWS * (D / 4);
    for (int64_t i = (int64_t)blockIdx.x * 256 + threadIdx.x; i < total4;
         i += (int64_t)gridDim.x * 256) {
        int row = (int)(i >> 17);  // D/4 = 2^17 float4 per row
        float tv = __uint_as_float(thr_bits[row]);
        float4 v = x[i];
        v.x = (v.x < tv) ? v.x : 0.0f;
        v.y = (v.y < tv) ? v.y : 0.0f;
        v.z = (v.z < tv) ? v.z : 0.0f;
        v.w = (v.w < tv) ? v.w : 0.0f;
        out[i] = v;
    }
}

extern "C" void kernel_launch(void* const* d_in, const int* in_sizes, int n_in,
                              void* d_out, int out_size, void* d_ws, size_t ws_size,
                              hipStream_t stream) {
    (void)in_sizes; (void)n_in; (void)out_size; (void)ws_size;
    const uint32_t* xu = (const uint32_t*)d_in[0];
    uint32_t* ws = (uint32_t*)d_ws;

    uint32_t* hist1 = ws;                        // 64*4096
    uint32_t* hist2 = ws + ROWS * 4096;          // 64*4096
    uint32_t* hist3 = ws + 2 * ROWS * 4096;      // 64*256
    uint32_t* ctrl  = hist3 + ROWS * 256;
    uint32_t* sel1  = ctrl;
    uint32_t* rank1 = ctrl + 64;
    uint32_t* sel2  = ctrl + 128;
    uint32_t* rank2 = ctrl + 192;
    uint32_t* thr   = ctrl + 256;

    // Zero all histogram storage every call (ws is not re-poisoned/zeroed
    // between replays; control words are fully rewritten by the selects).
    size_t zero_bytes = (size_t)(2 * ROWS * 4096 + ROWS * 256) * sizeof(uint32_t);
    hipMemsetAsync(d_ws, 0, zero_bytes, stream);

    hist_pass1<<<ROWS * BPR, 256, 0, stream>>>(xu, hist1);
    select_pass<4096><<<ROWS, 256, 0, stream>>>(hist1, 1, nullptr, sel1, rank1);
    hist_pass2<<<ROWS * BPR, 256, 0, stream>>>(xu, sel1, hist2);
    select_pass<4096><<<ROWS, 256, 0, stream>>>(hist2, 0, rank1, sel2, rank2);
    hist_pass3<<<ROWS * BPR, 256, 0, stream>>>(xu, sel1, sel2, hist3);
    select_final<<<ROWS, 256, 0, stream>>>(hist3, rank2, sel1, sel2, thr);
    mask_pass<<<2048, 256, 0, stream>>>((const float4*)d_in[0], (float4*)d_out, thr);
}

// Round 2
// 124.197 us; speedup vs baseline: 1.0798x; 1.0798x over previous
//
#include <hip/hip_runtime.h>
#include <stdint.h>

// Problem constants
constexpr int ROWS = 64;
constexpr int D = 1 << 19;          // 256*2048 = 524288 per row
constexpr uint32_t KSEL = 52428;    // int(0.1 * D)
constexpr int BPR = 32;             // blocks per row for scan passes
constexpr int CHUNK = D / BPR;      // 16384 elements per block
constexpr uint32_t CAND_MAX = 32768; // per-row candidate cap (expected ~11.5K)
constexpr int LBUF = 2048;          // per-block local candidate cap (expected ~360)

// Workspace layout (u32 indices)
constexpr size_t OFF_HIST1 = 0;                       // 64*4096
constexpr size_t OFF_CNT   = OFF_HIST1 + ROWS * 4096; // 64
constexpr size_t OFF_SEL1  = OFF_CNT + 64;            // 64
constexpr size_t OFF_RANK1 = OFF_SEL1 + 64;           // 64
constexpr size_t OFF_THR   = OFF_RANK1 + 64;          // 64
constexpr size_t OFF_CAND  = OFF_THR + 64;            // 64*CAND_MAX
constexpr size_t ZERO_U32  = OFF_CNT + 64;            // hist1 + cnt must be zeroed

// Monotonic key: larger float -> larger uint
__device__ __forceinline__ uint32_t mono(uint32_t f) {
    uint32_t m = (uint32_t)((int32_t)f >> 31) | 0x80000000u;
    return f ^ m;
}

// Zero hist1 + cnt (must precede hist_pass1 / compact each call).
__global__ __launch_bounds__(256) void zero_ws(uint32_t* __restrict__ ws) {
    const size_t n4 = (ZERO_U32 + 3) / 4;
    uint4* p = (uint4*)ws;
    for (size_t i = (size_t)blockIdx.x * 256 + threadIdx.x; i < n4;
         i += (size_t)gridDim.x * 256)
        p[i] = make_uint4(0, 0, 0, 0);
}

// Pass 1: 12-bit histogram of top bits of the key, per row.
__global__ __launch_bounds__(256) void hist_pass1(const uint32_t* __restrict__ x,
                                                  uint32_t* __restrict__ hist) {
    __shared__ uint32_t lh[4096];
    for (int i = threadIdx.x; i < 4096; i += 256) lh[i] = 0;
    __syncthreads();
    int row = blockIdx.x / BPR, chunk = blockIdx.x % BPR;
    const uint4* p = (const uint4*)(x + (size_t)row * D + (size_t)chunk * CHUNK);
    for (int i = threadIdx.x; i < CHUNK / 4; i += 256) {
        uint4 v = p[i];
        atomicAdd(&lh[mono(v.x) >> 20], 1u);
        atomicAdd(&lh[mono(v.y) >> 20], 1u);
        atomicAdd(&lh[mono(v.z) >> 20], 1u);
        atomicAdd(&lh[mono(v.w) >> 20], 1u);
    }
    __syncthreads();
    uint32_t* h = hist + row * 4096;
    for (int i = threadIdx.x; i < 4096; i += 256) {
        uint32_t c = lh[i];
        if (c) atomicAdd(&h[i], c);
    }
}

// Descending-order rank selection over 4096 bins: find bin where cumulative
// count (from the top bin down) first reaches k; output bin + residual rank.
__global__ __launch_bounds__(256) void select1(const uint32_t* __restrict__ hist,
                                               uint32_t* __restrict__ sel_out,
                                               uint32_t* __restrict__ rank_out) {
    constexpr int PER = 16;  // 4096 / 256
    __shared__ uint32_t sc[256];
    int row = blockIdx.x, t = threadIdx.x;
    const uint32_t* h = hist + row * 4096;
    uint32_t k = KSEL;
    int hi = 4095 - t * PER;  // thread t owns bins hi .. hi-PER+1 (descending)
    uint32_t s = 0;
    for (int j = 0; j < PER; ++j) s += h[hi - j];
    sc[t] = s;
    __syncthreads();
    for (int off = 1; off < 256; off <<= 1) {
        uint32_t v = (t >= off) ? sc[t - off] : 0u;
        __syncthreads();
        sc[t] += v;
        __syncthreads();
    }
    uint32_t excl = sc[t] - s;  // count in bins above this thread's group
    if (excl < k && excl + s >= k) {
        uint32_t c = excl;
        for (int j = 0; j < PER; ++j) {
            int bin = hi - j;
            uint32_t hb = h[bin];
            c += hb;
            if (c >= k) {
                sel_out[row] = (uint32_t)bin;
                rank_out[row] = k - (c - hb);
                break;
            }
        }
    }
}

// Compact keys matching the selected 12-bit prefix into per-row candidate
// buffers. LDS-aggregated: one global atomic per block.
__global__ __launch_bounds__(256) void compact(const uint32_t* __restrict__ x,
                                               const uint32_t* __restrict__ sel1v,
                                               uint32_t* __restrict__ cand,
                                               uint32_t* __restrict__ cnt) {
    __shared__ uint32_t lbuf[LBUF];
    __shared__ uint32_t ln;
    __shared__ uint32_t gbase;
    if (threadIdx.x == 0) ln = 0;
    __syncthreads();
    int row = blockIdx.x / BPR, chunk = blockIdx.x % BPR;
    uint32_t b1 = sel1v[row];
    const uint4* p = (const uint4*)(x + (size_t)row * D + (size_t)chunk * CHUNK);
    for (int i = threadIdx.x; i < CHUNK / 4; i += 256) {
        uint4 v = p[i];
        uint32_t u;
        u = mono(v.x); if ((u >> 20) == b1) { uint32_t s = atomicAdd(&ln, 1u); if (s < LBUF) lbuf[s] = u; }
        u = mono(v.y); if ((u >> 20) == b1) { uint32_t s = atomicAdd(&ln, 1u); if (s < LBUF) lbuf[s] = u; }
        u = mono(v.z); if ((u >> 20) == b1) { uint32_t s = atomicAdd(&ln, 1u); if (s < LBUF) lbuf[s] = u; }
        u = mono(v.w); if ((u >> 20) == b1) { uint32_t s = atomicAdd(&ln, 1u); if (s < LBUF) lbuf[s] = u; }
    }
    __syncthreads();
    uint32_t m = ln < (uint32_t)LBUF ? ln : (uint32_t)LBUF;
    if (threadIdx.x == 0) gbase = atomicAdd(&cnt[row], m);
    __syncthreads();
    uint32_t base = gbase;
    for (uint32_t i = threadIdx.x; i < m; i += 256) {
        uint32_t slot = base + i;
        if (slot < CAND_MAX) cand[(size_t)row * CAND_MAX + slot] = lbuf[i];
    }
}

// One block per row: exact select of rank1-th largest among candidates via
// two 10-bit LDS radix levels over the low 20 bits of the key.
__global__ __launch_bounds__(256) void final_select(const uint32_t* __restrict__ cand,
                                                    const uint32_t* __restrict__ cnt,
                                                    const uint32_t* __restrict__ sel1v,
                                                    const uint32_t* __restrict__ rank1v,
                                                    uint32_t* __restrict__ thr_bits) {
    __shared__ uint32_t h[1024];
    __shared__ uint32_t sc[256];
    __shared__ uint32_t bcast[2];
    int row = blockIdx.x, t = threadIdx.x;
    uint32_t n = cnt[row];
    if (n > CAND_MAX) n = CAND_MAX;
    const uint32_t* c = cand + (size_t)row * CAND_MAX;
    uint32_t k = rank1v[row];

    // Level 1: bits 19..10
    for (int i = t; i < 1024; i += 256) h[i] = 0;
    __syncthreads();
    for (uint32_t i = t; i < n; i += 256) atomicAdd(&h[(c[i] >> 10) & 0x3FFu], 1u);
    __syncthreads();
    {
        int hi = 1023 - t * 4;
        uint32_t s = 0;
        for (int j = 0; j < 4; ++j) s += h[hi - j];
        sc[t] = s;
        __syncthreads();
        for (int off = 1; off < 256; off <<= 1) {
            uint32_t v = (t >= off) ? sc[t - off] : 0u;
            __syncthreads();
            sc[t] += v;
            __syncthreads();
        }
        uint32_t excl = sc[t] - s;
        if (excl < k && excl + s >= k) {
            uint32_t cc = excl;
            for (int j = 0; j < 4; ++j) {
                int bin = hi - j;
                uint32_t hb = h[bin];
                cc += hb;
                if (cc >= k) { bcast[0] = (uint32_t)bin; bcast[1] = k - (cc - hb); break; }
            }
        }
    }
    __syncthreads();
    uint32_t b1 = bcast[0], k2 = bcast[1];
    __syncthreads();

    // Level 2: bits 9..0 among candidates matching b1
    for (int i = t; i < 1024; i += 256) h[i] = 0;
    __syncthreads();
    for (uint32_t i = t; i < n; i += 256) {
        uint32_t u = c[i];
        if (((u >> 10) & 0x3FFu) == b1) atomicAdd(&h[u & 0x3FFu], 1u);
    }
    __syncthreads();
    {
        int hi = 1023 - t * 4;
        uint32_t s = 0;
        for (int j = 0; j < 4; ++j) s += h[hi - j];
        sc[t] = s;
        __syncthreads();
        for (int off = 1; off < 256; off <<= 1) {
            uint32_t v = (t >= off) ? sc[t - off] : 0u;
            __syncthreads();
            sc[t] += v;
            __syncthreads();
        }
        uint32_t excl = sc[t] - s;
        if (excl < k2 && excl + s >= k2) {
            uint32_t cc = excl;
            for (int j = 0; j < 4; ++j) {
                int bin = hi - j;
                uint32_t hb = h[bin];
                cc += hb;
                if (cc >= k2) {
                    uint32_t u = (sel1v[row] << 20) | (b1 << 10) | (uint32_t)bin;
                    uint32_t m = (u & 0x80000000u) ? 0x80000000u : 0xFFFFFFFFu;
                    thr_bits[row] = u ^ m;  // float bits of exact K-th largest
                    break;
                }
            }
        }
    }
}

// Final mask: out = (x < thr) ? x : 0, float4-vectorized.
__global__ __launch_bounds__(256) void mask_pass(const float4* __restrict__ x,
                                                 float4* __restrict__ out,
                                                 const uint32_t* __restrict__ thr_bits) {
    const int64_t total4 = (int64_t)ROWS * (D / 4);
    for (int64_t i = (int64_t)blockIdx.x * 256 + threadIdx.x; i < total4;
         i += (int64_t)gridDim.x * 256) {
        int row = (int)(i >> 17);  // D/4 = 2^17 float4 per row
        float tv = __uint_as_float(thr_bits[row]);
        float4 v = x[i];
        v.x = (v.x < tv) ? v.x : 0.0f;
        v.y = (v.y < tv) ? v.y : 0.0f;
        v.z = (v.z < tv) ? v.z : 0.0f;
        v.w = (v.w < tv) ? v.w : 0.0f;
        out[i] = v;
    }
}

extern "C" void kernel_launch(void* const* d_in, const int* in_sizes, int n_in,
                              void* d_out, int out_size, void* d_ws, size_t ws_size,
                              hipStream_t stream) {
    (void)in_sizes; (void)n_in; (void)out_size; (void)ws_size;
    const uint32_t* xu = (const uint32_t*)d_in[0];
    uint32_t* ws = (uint32_t*)d_ws;

    uint32_t* hist1 = ws + OFF_HIST1;
    uint32_t* cnt   = ws + OFF_CNT;
    uint32_t* sel1v = ws + OFF_SEL1;
    uint32_t* rank1 = ws + OFF_RANK1;
    uint32_t* thr   = ws + OFF_THR;
    uint32_t* cand  = ws + OFF_CAND;

    zero_ws<<<128, 256, 0, stream>>>(ws);
    hist_pass1<<<ROWS * BPR, 256, 0, stream>>>(xu, hist1);
    select1<<<ROWS, 256, 0, stream>>>(hist1, sel1v, rank1);
    compact<<<ROWS * BPR, 256, 0, stream>>>(xu, sel1v, cand, cnt);
    final_select<<<ROWS, 256, 0, stream>>>(cand, cnt, sel1v, rank1, thr);
    mask_pass<<<4096, 256, 0, stream>>>((const float4*)d_in[0], (float4*)d_out, thr);
}